// Round 10
// baseline (244.237 us; speedup 1.0000x reference)
//
#include <hip/hip_runtime.h>
#include <hip/hip_fp16.h>

// GCN 2-layer forward on MI355X — R20: R19 + (1) k_agg2 act-guard: only
// lanes f<20 gather (f>=20 fetched 37.5% garbage cols and discarded them)
// and g packed to GP=40 halves (80 B rows; 12.8 -> 8 MB footprint);
// (2) W2TS 72 -> 68 (34-dword stride): MFMA b64 LDS reads hit the uniform
// 4-access/bank floor, killing the 1.2M bank conflicts R19 introduced.
// Kept: MFMA GEMM1 + MFMA GEMM2 (hi/lo fp16, fp32-grade), R17 agg loops,
// x8-padded esrc, deg from k_bucket, unroll-1 pins.
// Pipeline: hist -> scan(+W1t,W2t) -> scatter -> bucket(deg) -> gemm1m -> agg1mm -> agg2
// d_in: [0]=x (N*128 f32), [1]=edge_index (2*E i32), [2]=W1 (128*64),
//       [3]=b1 (64), [4]=W2 (64*40), [5]=b2 (40)
// d_out: N*40 f32

#define FIN 128
#define H1  64
#define C2  40
#define GP  40            // packed row stride (halves) for g => 80 B rows
#define TILE 8192         // edges per hist/scatter tile
#define BCAP 7168         // padded bucket capacity (mean 4096 + <=1792 pad)
#define WTS 132           // padded W1t row stride (halves): bank-conflict-free
#define W2TS 68           // padded W2t/hs row stride (halves): 34-dword => bank floor

typedef _Float16 half4_t __attribute__((ext_vector_type(4)));
typedef float float4_t __attribute__((ext_vector_type(4)));

// ---------- histogram: per-bucket counts only (LDS atomics) ----------
__global__ __launch_bounds__(256) void k_hist(const int* __restrict__ col, int E,
                                              int* __restrict__ bucketCnt, int NB) {
    __shared__ int lh[512];
    int t = threadIdx.x;
    for (int i = t; i < NB; i += 256) lh[i] = 0;
    __syncthreads();
    int base = blockIdx.x * TILE;
    int cnt = min(TILE, E - base);
    for (int i = t; i < cnt; i += 256) atomicAdd(&lh[col[base + i] >> 8], 1);
    __syncthreads();
    for (int b = t; b < NB; b += 256) if (lh[b]) atomicAdd(&bucketCnt[b], lh[b]);
}

// ---------- scan over NB buckets; sentinel rows; W1/W2 -> hi/lo fp16 planes ----------
__global__ __launch_bounds__(512) void k_scan(const int* __restrict__ bucketCnt,
                                              int* __restrict__ rawBase,
                                              int* __restrict__ padBase,
                                              int* __restrict__ gcursor,
                                              __half* __restrict__ h1,
                                              __half* __restrict__ g,
                                              const float* __restrict__ W1,
                                              _Float16* __restrict__ W1th,
                                              _Float16* __restrict__ W1tl,
                                              const float* __restrict__ W2,
                                              _Float16* __restrict__ W2th,
                                              _Float16* __restrict__ W2tl,
                                              int NB, int N) {
    __shared__ int sr[512], sp[512];
    int t = threadIdx.x;
    int c = (t < NB) ? bucketCnt[t] : 0;
    int p = (t < NB) ? (((c + 7) & ~7) + 2048) : 0;   // room for per-dest x8 pad
    sr[t] = c; sp[t] = p;
    __syncthreads();
    for (int off = 1; off < 512; off <<= 1) {
        int a = (t >= off) ? sr[t - off] : 0;
        int b = (t >= off) ? sp[t - off] : 0;
        __syncthreads();
        sr[t] += a; sp[t] += b;
        __syncthreads();
    }
    if (t <= NB) {
        rawBase[t] = sr[t] - ((t < NB) ? c : 0);
        padBase[t] = sp[t] - ((t < NB) ? p : 0);
        if (t < NB) gcursor[t] = sr[t] - c;
    }
    // sentinel rows: pad entries reference src == N and must contribute 0
    if (t < 32) ((unsigned*)(h1 + (size_t)N * H1))[t] = 0u;            // 64 halves
    else if (t < 52) ((unsigned*)(g + (size_t)N * GP))[t - 32] = 0u;   // 40 halves
    // W1 (fp32 [k][o]) -> transposed padded hi/lo fp16 planes [o][WTS]
    for (int i = t; i < FIN * H1; i += 512) {
        int o = i >> 7, k = i & 127;
        float wv = W1[k * H1 + o];
        _Float16 hi = (_Float16)wv;
        W1th[o * WTS + k] = hi;
        W1tl[o * WTS + k] = (_Float16)(wv - (float)hi);
    }
    // W2 (fp32 [k][c]) -> transposed padded hi/lo fp16 planes [n][W2TS], n<48
    for (int i = t; i < 48 * 64; i += 512) {
        int n = i >> 6, kk = i & 63;
        float wv = (n < C2) ? W2[kk * C2 + n] : 0.f;
        _Float16 hi = (_Float16)wv;
        W2th[n * W2TS + kk] = hi;
        W2tl[n * W2TS + kk] = (_Float16)(wv - (float)hi);
    }
}

// ---------- scatter into bucket-contiguous chunks (packed pairs) ----------
// packed: bits 0..23 = src row, bits 24..31 = dest low 8
__global__ __launch_bounds__(512) void k_scatter(const int* __restrict__ row,
                                                 const int* __restrict__ col,
                                                 int* __restrict__ gcursor,
                                                 int* __restrict__ pairs,
                                                 int E, int NB) {
    __shared__ int2 stage[TILE];         // 64 KB
    __shared__ int lcnt[512];
    __shared__ int lex[512];
    __shared__ int gbase[512];
    int t = threadIdx.x, tile = blockIdx.x;
    int base = tile * TILE;
    int cnt = min(TILE, E - base);

    lcnt[t] = 0;
    __syncthreads();
    for (int i = t; i < cnt; i += 512) atomicAdd(&lcnt[col[base + i] >> 8], 1);
    __syncthreads();

    int myc = lcnt[t];
    lex[t] = myc;
    __syncthreads();
    for (int off = 1; off < 512; off <<= 1) {
        int u = (t >= off) ? lex[t - off] : 0;
        __syncthreads();
        lex[t] += u;
        __syncthreads();
    }
    int ex = lex[t] - myc;
    __syncthreads();
    lex[t] = ex;
    lcnt[t] = ex;                         // local cursor
    if (t < NB && myc > 0) gbase[t] = atomicAdd(&gcursor[t], myc);
    __syncthreads();

    for (int i = t; i < cnt; i += 512) {
        int r = row[base + i], c = col[base + i];
        int lpos = atomicAdd(&lcnt[c >> 8], 1);
        stage[lpos] = make_int2(r, c);
    }
    __syncthreads();

    for (int i = t; i < cnt; i += 512) {
        int2 p = stage[i];
        int b = p.y >> 8;
        pairs[gbase[b] + (i - lex[b])] = p.x | ((p.y & 255) << 24);
    }
}

// ---------- per-bucket final sort by dest; x8-padded esrc segments; deg ----------
__global__ __launch_bounds__(512) void k_bucket(const int* __restrict__ pairs,
                                                const int* __restrict__ rawBase,
                                                const int* __restrict__ padBase,
                                                int* __restrict__ rowptr,
                                                int* __restrict__ deg,
                                                int* __restrict__ esrc,
                                                int N, int NB) {
    __shared__ int dcnt[256];
    __shared__ int sr[256], sp[256];
    __shared__ int cur[256];
    __shared__ int outbuf[BCAP];         // 28 KB
    int t = threadIdx.x, b = blockIdx.x;
    int d0 = b << 8;
    int nd = min(256, N - d0);
    int bstart = rawBase[b];
    int cnt = rawBase[b + 1] - bstart;
    int pstart = padBase[b];

    if (t < 256) dcnt[t] = 0;
    __syncthreads();
    for (int i = t; i < cnt; i += 512) {
        unsigned p = (unsigned)pairs[bstart + i];
        atomicAdd(&dcnt[p >> 24], 1);
    }
    __syncthreads();

    int myc = 0, myp = 0;
    if (t < 256) {
        myc = dcnt[t];
        myp = (myc + 7) & ~7;
        sr[t] = myc; sp[t] = myp;
    }
    __syncthreads();
    for (int off = 1; off < 256; off <<= 1) {
        int a = 0, c2 = 0;
        if (t < 256 && t >= off) { a = sr[t - off]; c2 = sp[t - off]; }
        __syncthreads();
        if (t < 256) { sr[t] += a; sp[t] += c2; }
        __syncthreads();
    }
    if (t < 256) {
        int pex = sp[t] - myp;
        cur[t] = pex;
        if (t < nd) {
            rowptr[d0 + t] = pstart + pex;
            deg[d0 + t] = myc;            // degree for free
        }
    }
    __syncthreads();
    int pcnt = sp[255];

    if (pcnt <= BCAP) {
        for (int i = t; i < cnt; i += 512) {
            unsigned p = (unsigned)pairs[bstart + i];
            int lpos = atomicAdd(&cur[p >> 24], 1);
            outbuf[lpos] = (int)(p & 0xFFFFFF);
        }
        __syncthreads();
        if (t < 256) {
            int pex = sp[t] - myp;
            for (int j = myc; j < myp; ++j) outbuf[pex + j] = N;   // sentinel pad
        }
        __syncthreads();
        for (int i = t; i < pcnt; i += 512) esrc[pstart + i] = outbuf[i];
    } else {
        for (int i = t; i < cnt; i += 512) {
            unsigned p = (unsigned)pairs[bstart + i];
            int lpos = atomicAdd(&cur[p >> 24], 1);
            esrc[pstart + lpos] = (int)(p & 0xFFFFFF);
        }
        __syncthreads();
        if (t < 256) {
            int pex = sp[t] - myp;
            for (int j = myc; j < myp; ++j) esrc[pstart + pex + j] = N;
        }
    }
}

// ---------- GEMM1 via MFMA: h1' = (x@W1)*dinv, hi/lo fp16 split ----------
__global__ __launch_bounds__(256) void k_gemm1m(const float* __restrict__ x,
                                                const _Float16* __restrict__ W1th,
                                                const _Float16* __restrict__ W1tl,
                                                const int* __restrict__ deg,
                                                __half* __restrict__ h1, int N) {
    __shared__ alignas(16) _Float16 Wh[H1 * WTS];   // 16.5 KB
    __shared__ alignas(16) _Float16 Wl[H1 * WTS];   // 16.5 KB
    int t = threadIdx.x;

    {   // stage both planes: 8448 halves = 1056 uint4 each
        const uint4* sh = (const uint4*)W1th;
        const uint4* sl = (const uint4*)W1tl;
        uint4* dh = (uint4*)Wh;
        uint4* dl = (uint4*)Wl;
        for (int i = t; i < (H1 * WTS) / 8; i += 256) { dh[i] = sh[i]; dl[i] = sl[i]; }
    }

    int wv = t >> 6, l = t & 63;
    int col = l & 15;             // node within 16-tile (and A-row lane index)
    int krow = l >> 4;            // 0..3
    int node = blockIdx.x * 64 + wv * 16 + col;
    int nodec = min(node, N - 1);

    // B fragments from x: lane holds x[node][kt*16 + krow*4 + 0..3]
    half4_t bh[8], bl[8];
    const float4* xr = (const float4*)(x + (size_t)nodec * FIN);
#pragma unroll
    for (int kt = 0; kt < 8; ++kt) {
        float4 v = xr[kt * 4 + krow];
        half4_t hi, lo;
        hi[0] = (_Float16)v.x; lo[0] = (_Float16)(v.x - (float)hi[0]);
        hi[1] = (_Float16)v.y; lo[1] = (_Float16)(v.y - (float)hi[1]);
        hi[2] = (_Float16)v.z; lo[2] = (_Float16)(v.z - (float)hi[2]);
        hi[3] = (_Float16)v.w; lo[3] = (_Float16)(v.w - (float)hi[3]);
        bh[kt] = hi; bl[kt] = lo;
    }
    float dcv = rsqrtf((float)deg[nodec] + 1.0f);
    __syncthreads();

    float4_t acc[4];
#pragma unroll
    for (int ot = 0; ot < 4; ++ot) acc[ot] = (float4_t){0.f, 0.f, 0.f, 0.f};

#pragma unroll
    for (int kt = 0; kt < 8; ++kt) {
#pragma unroll
        for (int ot = 0; ot < 4; ++ot) {
            int aoff = ((ot * 16 + col) * WTS + kt * 16 + krow * 4) >> 2;  // half4 units
            half4_t ah = ((const half4_t*)Wh)[aoff];
            half4_t al = ((const half4_t*)Wl)[aoff];
            acc[ot] = __builtin_amdgcn_mfma_f32_16x16x16f16(ah, bh[kt], acc[ot], 0, 0, 0);
            acc[ot] = __builtin_amdgcn_mfma_f32_16x16x16f16(ah, bl[kt], acc[ot], 0, 0, 0);
            acc[ot] = __builtin_amdgcn_mfma_f32_16x16x16f16(al, bh[kt], acc[ot], 0, 0, 0);
        }
    }

    if (node < N) {
#pragma unroll
        for (int ot = 0; ot < 4; ++ot) {
            union { __half h[4]; uint2 u; } pk;
#pragma unroll
            for (int r = 0; r < 4; ++r) pk.h[r] = __float2half_rn(acc[ot][r] * dcv);
            *(uint2*)&h1[(size_t)node * H1 + ot * 16 + krow * 4] = pk.u;
        }
    }
}

// ---------- fused agg1 + bias + ReLU + GEMM2(MFMA) per 64-node block ----------
// 512 threads = 8 waves. Aggregation: EXACT R17 shape. Epilogue writes hs
// as hi/lo fp16 planes (stride W2TS=68: MFMA b64 reads at the bank floor).
// GEMM2: 12 16x16 MFMA tiles over 8 waves, 3 mfma per k-step (fp32-grade).
__global__ __launch_bounds__(512) void k_agg1mm(const int* __restrict__ rowptr,
                                                const int* __restrict__ deg,
                                                const int* __restrict__ esrc,
                                                const __half* __restrict__ h1,
                                                const float* __restrict__ b1,
                                                const _Float16* __restrict__ W2th,
                                                const _Float16* __restrict__ W2tl,
                                                __half* __restrict__ g, int N) {
    __shared__ alignas(16) _Float16 hsh[64][W2TS];   // 8.7 KB
    __shared__ alignas(16) _Float16 hsl[64][W2TS];   // 8.7 KB
    __shared__ alignas(16) _Float16 Wth[48][W2TS];   // 6.5 KB
    __shared__ alignas(16) _Float16 Wtl[48][W2TS];   // 6.5 KB
    __shared__ float sdc[64];
    int t = threadIdx.x;
    int node0 = blockIdx.x * 64;

    {   // stage W2t planes: 408 uint4 each
        const uint4* sh = (const uint4*)W2th;
        const uint4* sl = (const uint4*)W2tl;
        uint4* dh = (uint4*)Wth;
        uint4* dl = (uint4*)Wtl;
        for (int i = t; i < (48 * W2TS) / 8; i += 512) { dh[i] = sh[i]; dl[i] = sl[i]; }
    }

    int wv = t >> 6, lane = t & 63;
    int half = lane >> 5;                // edge-octet selector
    int f = lane & 31;                   // feature-pair index
    float2 b1v = *(const float2*)&b1[2 * f];
    const __half2* hp = (const __half2*)h1;

    // aggregation: 8 nodes per wave, sequential (EXACT R17 loop)
#pragma unroll 1
    for (int j = 0; j < 8; ++j) {
        int r = wv * 8 + j;
        int node = node0 + r;
        if (node >= N) {
            if (lane < 32) { *(unsigned*)&hsh[r][2 * f] = 0u; *(unsigned*)&hsl[r][2 * f] = 0u; }
            if (lane == 0) sdc[r] = 0.f;
            continue;
        }
        int start = rowptr[node], d = deg[node];
        int d8 = (d + 7) & ~7;
        float dc = rsqrtf((float)d + 1.0f);
        float ax = 0.f, ay = 0.f;
        int i = 0;
#pragma unroll 1
        for (; i + 16 <= d8; i += 16) {
            int b0 = start + i + half * 8;
            int4 sA = *(const int4*)&esrc[b0];
            int4 sB = *(const int4*)&esrc[b0 + 4];
            float2 v0 = __half22float2(hp[sA.x * 32 + f]);
            float2 v1 = __half22float2(hp[sA.y * 32 + f]);
            float2 v2 = __half22float2(hp[sA.z * 32 + f]);
            float2 v3 = __half22float2(hp[sA.w * 32 + f]);
            float2 v4 = __half22float2(hp[sB.x * 32 + f]);
            float2 v5 = __half22float2(hp[sB.y * 32 + f]);
            float2 v6 = __half22float2(hp[sB.z * 32 + f]);
            float2 v7 = __half22float2(hp[sB.w * 32 + f]);
            ax += ((v0.x + v1.x) + (v2.x + v3.x)) + ((v4.x + v5.x) + (v6.x + v7.x));
            ay += ((v0.y + v1.y) + (v2.y + v3.y)) + ((v4.y + v5.y) + (v6.y + v7.y));
        }
        if (i < d8) {                    // one 8-edge chunk: 4 per half
            int4 s = *(const int4*)&esrc[start + i + half * 4];
            float2 v0 = __half22float2(hp[s.x * 32 + f]);
            float2 v1 = __half22float2(hp[s.y * 32 + f]);
            float2 v2 = __half22float2(hp[s.z * 32 + f]);
            float2 v3 = __half22float2(hp[s.w * 32 + f]);
            ax += (v0.x + v1.x) + (v2.x + v3.x);
            ay += (v0.y + v1.y) + (v2.y + v3.y);
        }
        // cross-half reduce (both halves end with full sum)
        ax += __shfl(ax, lane ^ 32);
        ay += __shfl(ay, lane ^ 32);
        // self-loop (h1' already has one dinv factor) + bias + ReLU
        float2 sv = __half22float2(hp[node * 32 + f]);
        ax = fmaxf(fmaf(dc, ax + sv.x, b1v.x), 0.f);
        ay = fmaxf(fmaf(dc, ay + sv.y, b1v.y), 0.f);
        if (lane < 32) {
            // hi/lo fp16 split (exact): hs = hi + lo to ~2^-22
            _Float16 axh = (_Float16)ax;
            _Float16 ayh = (_Float16)ay;
            _Float16 axl = (_Float16)(ax - (float)axh);
            _Float16 ayl = (_Float16)(ay - (float)ayh);
            union { _Float16 h[2]; unsigned u; } ph, pl;
            ph.h[0] = axh; ph.h[1] = ayh;
            pl.h[0] = axl; pl.h[1] = ayl;
            *(unsigned*)&hsh[r][2 * f] = ph.u;
            *(unsigned*)&hsl[r][2 * f] = pl.u;
        }
        if (lane == 0) sdc[r] = dc;
    }
    __syncthreads();

    // GEMM2 via MFMA: D[64 nodes][48 cols] = hs(h/l) x W2t(h/l); 12 tiles / 8 waves.
    int l15 = lane & 15, kg = (lane >> 4) * 4;
#pragma unroll 1
    for (int tile = wv; tile < 12; tile += 8) {
        int mt = tile & 3, nt = tile >> 2;
        int arow = mt * 16 + l15;
        int bcol = nt * 16 + l15;
        float4_t acc = (float4_t){0.f, 0.f, 0.f, 0.f};
#pragma unroll
        for (int kt = 0; kt < 4; ++kt) {
            int ko = kt * 16 + kg;
            half4_t ah = *(const half4_t*)&hsh[arow][ko];
            half4_t al = *(const half4_t*)&hsl[arow][ko];
            half4_t bh = *(const half4_t*)&Wth[bcol][ko];
            half4_t bl = *(const half4_t*)&Wtl[bcol][ko];
            acc = __builtin_amdgcn_mfma_f32_16x16x16f16(ah, bh, acc, 0, 0, 0);
            acc = __builtin_amdgcn_mfma_f32_16x16x16f16(ah, bl, acc, 0, 0, 0);
            acc = __builtin_amdgcn_mfma_f32_16x16x16f16(al, bh, acc, 0, 0, 0);
        }
        int colo = nt * 16 + l15;
        if (colo < C2) {                 // cols 40-47 are zero; only <40 stored
#pragma unroll
            for (int r2 = 0; r2 < 4; ++r2) {
                int nd = mt * 16 + (lane >> 4) * 4 + r2;
                int node = node0 + nd;
                if (node < N) {
                    g[(size_t)node * GP + colo] = __float2half_rn(acc[r2] * sdc[nd]);
                }
            }
        }
    }
}

// ---------- agg2: wave per node, packed g rows, act-guarded gathers ----------
__global__ __launch_bounds__(256) void k_agg2(const int* __restrict__ rowptr,
                                              const int* __restrict__ deg,
                                              const int* __restrict__ esrc,
                                              const __half* __restrict__ g,
                                              const float* __restrict__ b2,
                                              float* __restrict__ out, int N) {
    int w = (int)((blockIdx.x * blockDim.x + threadIdx.x) >> 6);
    int lane = threadIdx.x & 63;
    if (w >= N) return;
    int half = lane >> 5;
    int f = lane & 31;                   // feature-pair; active f<20
    bool act = f < 20;
    const __half2* gp = (const __half2*)g;  // row stride 20 half2 (80 B)

    int start = rowptr[w], d = deg[w];
    int d8 = (d + 7) & ~7;
    float dc = rsqrtf((float)d + 1.0f);
    float ax = 0.f, ay = 0.f;
    if (act) {                           // f>=20 lanes: no gathers (saved 37.5%)
        int i = 0;
#pragma unroll 1
        for (; i + 16 <= d8; i += 16) {
            int b0 = start + i + half * 8;
            int4 sA = *(const int4*)&esrc[b0];
            int4 sB = *(const int4*)&esrc[b0 + 4];
            float2 v0 = __half22float2(gp[sA.x * 20 + f]);
            float2 v1 = __half22float2(gp[sA.y * 20 + f]);
            float2 v2 = __half22float2(gp[sA.z * 20 + f]);
            float2 v3 = __half22float2(gp[sA.w * 20 + f]);
            float2 v4 = __half22float2(gp[sB.x * 20 + f]);
            float2 v5 = __half22float2(gp[sB.y * 20 + f]);
            float2 v6 = __half22float2(gp[sB.z * 20 + f]);
            float2 v7 = __half22float2(gp[sB.w * 20 + f]);
            ax += ((v0.x + v1.x) + (v2.x + v3.x)) + ((v4.x + v5.x) + (v6.x + v7.x));
            ay += ((v0.y + v1.y) + (v2.y + v3.y)) + ((v4.y + v5.y) + (v6.y + v7.y));
        }
        if (i < d8) {
            int4 s = *(const int4*)&esrc[start + i + half * 4];
            float2 v0 = __half22float2(gp[s.x * 20 + f]);
            float2 v1 = __half22float2(gp[s.y * 20 + f]);
            float2 v2 = __half22float2(gp[s.z * 20 + f]);
            float2 v3 = __half22float2(gp[s.w * 20 + f]);
            ax += (v0.x + v1.x) + (v2.x + v3.x);
            ay += (v0.y + v1.y) + (v2.y + v3.y);
        }
    }
    ax += __shfl(ax, lane ^ 32);
    ay += __shfl(ay, lane ^ 32);
    if (lane < 32 && act) {
        float2 b2v = *(const float2*)&b2[2 * f];
        float2 sv = __half22float2(gp[w * 20 + f]);
        float2 o;
        o.x = fmaf(dc, ax + sv.x, b2v.x);
        o.y = fmaf(dc, ay + sv.y, b2v.y);
        *(float2*)&out[(size_t)w * C2 + 2 * f] = o;
    }
}

extern "C" void kernel_launch(void* const* d_in, const int* in_sizes, int n_in,
                              void* d_out, int out_size, void* d_ws, size_t ws_size,
                              hipStream_t stream) {
    const float* x   = (const float*)d_in[0];
    const int*   ei  = (const int*)d_in[1];
    const float* W1  = (const float*)d_in[2];
    const float* b1  = (const float*)d_in[3];
    const float* W2  = (const float*)d_in[4];
    const float* b2  = (const float*)d_in[5];
    float* out = (float*)d_out;

    const int N = in_sizes[0] / FIN;       // 100000
    const int E = in_sizes[1] / 2;         // 1600000
    const int* row = ei;
    const int* col = ei + E;

    const int NB = (N + 255) >> 8;         // 391 buckets
    const int T  = (E + TILE - 1) / TILE;  // 196 tiles
    const int EP = E + NB * 2048 + 1024;   // padded esrc capacity (x8 pad)

    // workspace layout
    char* ws = (char*)d_ws;
    size_t off = 0;
    int*    bucketCnt = (int*)(ws + off);    off += (size_t)NB * 4;
    int*    rawBase   = (int*)(ws + off);    off += (size_t)(NB + 1) * 4;
    int*    padBase   = (int*)(ws + off);    off += (size_t)(NB + 1) * 4;
    int*    gcursor   = (int*)(ws + off);    off += (size_t)NB * 4;
    int*    deg       = (int*)(ws + off);    off += (size_t)N * 4;
    int*    rowptr    = (int*)(ws + off);    off += (size_t)N * 4;
    int*    pairs     = (int*)(ws + off);    off += (size_t)E * 4;
    off = (off + 15) & ~(size_t)15;
    int*    esrc      = (int*)(ws + off);    off += (size_t)EP * 4;
    off = (off + 15) & ~(size_t)15;
    _Float16* W1th    = (_Float16*)(ws + off); off += (size_t)H1 * WTS * 2;
    off = (off + 15) & ~(size_t)15;
    _Float16* W1tl    = (_Float16*)(ws + off); off += (size_t)H1 * WTS * 2;
    off = (off + 15) & ~(size_t)15;
    _Float16* W2th    = (_Float16*)(ws + off); off += (size_t)48 * W2TS * 2;
    off = (off + 15) & ~(size_t)15;
    _Float16* W2tl    = (_Float16*)(ws + off); off += (size_t)48 * W2TS * 2;
    off = (off + 15) & ~(size_t)15;
    __half* h1        = (__half*)(ws + off); off += (size_t)(N + 1) * H1 * 2;
    off = (off + 15) & ~(size_t)15;
    __half* g         = (__half*)(ws + off); off += (size_t)(N + 1) * GP * 2;

    hipMemsetAsync(bucketCnt, 0, (size_t)NB * 4, stream);

    int gblocks = (N + 63) / 64;           // 1563

    // CSR build: bucket histogram -> scan (+W1t/W2t planes) -> chunk-claim
    // scatter -> bucket sort (emits deg for free)
    k_hist<<<T, 256, 0, stream>>>(col, E, bucketCnt, NB);
    k_scan<<<1, 512, 0, stream>>>(bucketCnt, rawBase, padBase, gcursor, h1, g,
                                  W1, W1th, W1tl, W2, W2th, W2tl, NB, N);
    k_scatter<<<T, 512, 0, stream>>>(row, col, gcursor, pairs, E, NB);
    k_bucket<<<NB, 512, 0, stream>>>(pairs, rawBase, padBase, rowptr, deg, esrc, N, NB);

    // GEMM1 via MFMA, writes h1' = (x@W1)*dinv (needs deg => after k_bucket)
    k_gemm1m<<<gblocks, 256, 0, stream>>>(x, W1th, W1tl, deg, h1, N);

    // layer 1 aggregation + bias + ReLU + GEMM2 via MFMA (fused), writes g' = h2*dinv
    k_agg1mm<<<gblocks, 512, 0, stream>>>(rowptr, deg, esrc, h1, b1, W2th, W2tl, g, N);

    // layer 2 aggregation + bias
    k_agg2<<<((size_t)N * 64 + 255) / 256, 256, 0, stream>>>(rowptr, deg, esrc, g, b2, out, N);
}

// Round 11
// 238.387 us; speedup vs baseline: 1.0245x; 1.0245x over previous
//
#include <hip/hip_runtime.h>
#include <hip/hip_fp16.h>

// GCN 2-layer forward on MI355X — R21: R20 + (1) software-pipelined esrc
// index loads in both agg kernels (prefetch next iteration's int4s while
// current gathers are in flight — kills the exposed ~300cy index latency
// per 16 edges); esrc gets a +8K-int tail guard making over-read safe (and
// fixing a marginal EP bound). (2) W1/W2 hi/lo transposes moved out of the
// single-block k_scan (uncoalesced, serial ~5-10us) into parallel k_wprep
// (44 blocks, coalesced reads, scattered writes).
// Kept: MFMA GEMM1+GEMM2 (hi/lo fp16, fp32-grade), R17 agg loops, W2TS=68
// (bank floor, R20: conflicts 1.2M->0), GP=40 packed g, x8-padded esrc,
// deg from k_bucket, unroll-1 pins.
// Pipeline: wprep -> hist -> scan -> scatter -> bucket(deg) -> gemm1m -> agg1mm -> agg2
// d_in: [0]=x (N*128 f32), [1]=edge_index (2*E i32), [2]=W1 (128*64),
//       [3]=b1 (64), [4]=W2 (64*40), [5]=b2 (40)
// d_out: N*40 f32

#define FIN 128
#define H1  64
#define C2  40
#define GP  40            // packed row stride (halves) for g => 80 B rows
#define TILE 8192         // edges per hist/scatter tile
#define BCAP 7168         // padded bucket capacity (mean 4096 + <=1792 pad)
#define WTS 132           // padded W1t row stride (halves): bank-conflict-free
#define W2TS 68           // padded W2t/hs row stride (halves): 34-dword => bank floor

typedef _Float16 half4_t __attribute__((ext_vector_type(4)));
typedef float float4_t __attribute__((ext_vector_type(4)));

// ---------- W1/W2 -> transposed hi/lo fp16 planes (parallel, coalesced reads) ----------
__global__ __launch_bounds__(256) void k_wprep(const float* __restrict__ W1,
                                               _Float16* __restrict__ W1th,
                                               _Float16* __restrict__ W1tl,
                                               const float* __restrict__ W2,
                                               _Float16* __restrict__ W2th,
                                               _Float16* __restrict__ W2tl) {
    int idx = blockIdx.x * 256 + threadIdx.x;
    if (idx < FIN * H1) {
        // W1 [k][o] -> planes [o][WTS]; consecutive idx = consecutive o (coalesced read)
        int k = idx >> 6, o = idx & 63;
        float wv = W1[k * H1 + o];
        _Float16 hi = (_Float16)wv;
        W1th[o * WTS + k] = hi;
        W1tl[o * WTS + k] = (_Float16)(wv - (float)hi);
    } else if (idx < FIN * H1 + 48 * 64) {
        // W2 [k][c] -> planes [n][W2TS], n<48 (cols 40-47 zero); coalesced over n
        int i = idx - FIN * H1;
        int kk = i / 48, n = i % 48;
        float wv = (n < C2) ? W2[kk * C2 + n] : 0.f;
        _Float16 hi = (_Float16)wv;
        W2th[n * W2TS + kk] = hi;
        W2tl[n * W2TS + kk] = (_Float16)(wv - (float)hi);
    }
}

// ---------- histogram: per-bucket counts only (LDS atomics) ----------
__global__ __launch_bounds__(256) void k_hist(const int* __restrict__ col, int E,
                                              int* __restrict__ bucketCnt, int NB) {
    __shared__ int lh[512];
    int t = threadIdx.x;
    for (int i = t; i < NB; i += 256) lh[i] = 0;
    __syncthreads();
    int base = blockIdx.x * TILE;
    int cnt = min(TILE, E - base);
    for (int i = t; i < cnt; i += 256) atomicAdd(&lh[col[base + i] >> 8], 1);
    __syncthreads();
    for (int b = t; b < NB; b += 256) if (lh[b]) atomicAdd(&bucketCnt[b], lh[b]);
}

// ---------- scan over NB buckets; sentinel rows ----------
__global__ __launch_bounds__(512) void k_scan(const int* __restrict__ bucketCnt,
                                              int* __restrict__ rawBase,
                                              int* __restrict__ padBase,
                                              int* __restrict__ gcursor,
                                              __half* __restrict__ h1,
                                              __half* __restrict__ g,
                                              int NB, int N) {
    __shared__ int sr[512], sp[512];
    int t = threadIdx.x;
    int c = (t < NB) ? bucketCnt[t] : 0;
    int p = (t < NB) ? (((c + 7) & ~7) + 2048) : 0;   // room for per-dest x8 pad
    sr[t] = c; sp[t] = p;
    __syncthreads();
    for (int off = 1; off < 512; off <<= 1) {
        int a = (t >= off) ? sr[t - off] : 0;
        int b = (t >= off) ? sp[t - off] : 0;
        __syncthreads();
        sr[t] += a; sp[t] += b;
        __syncthreads();
    }
    if (t <= NB) {
        rawBase[t] = sr[t] - ((t < NB) ? c : 0);
        padBase[t] = sp[t] - ((t < NB) ? p : 0);
        if (t < NB) gcursor[t] = sr[t] - c;
    }
    // sentinel rows: pad entries reference src == N and must contribute 0
    if (t < 32) ((unsigned*)(h1 + (size_t)N * H1))[t] = 0u;            // 64 halves
    else if (t < 52) ((unsigned*)(g + (size_t)N * GP))[t - 32] = 0u;   // 40 halves
}

// ---------- scatter into bucket-contiguous chunks (packed pairs) ----------
// packed: bits 0..23 = src row, bits 24..31 = dest low 8
__global__ __launch_bounds__(512) void k_scatter(const int* __restrict__ row,
                                                 const int* __restrict__ col,
                                                 int* __restrict__ gcursor,
                                                 int* __restrict__ pairs,
                                                 int E, int NB) {
    __shared__ int2 stage[TILE];         // 64 KB
    __shared__ int lcnt[512];
    __shared__ int lex[512];
    __shared__ int gbase[512];
    int t = threadIdx.x, tile = blockIdx.x;
    int base = tile * TILE;
    int cnt = min(TILE, E - base);

    lcnt[t] = 0;
    __syncthreads();
    for (int i = t; i < cnt; i += 512) atomicAdd(&lcnt[col[base + i] >> 8], 1);
    __syncthreads();

    int myc = lcnt[t];
    lex[t] = myc;
    __syncthreads();
    for (int off = 1; off < 512; off <<= 1) {
        int u = (t >= off) ? lex[t - off] : 0;
        __syncthreads();
        lex[t] += u;
        __syncthreads();
    }
    int ex = lex[t] - myc;
    __syncthreads();
    lex[t] = ex;
    lcnt[t] = ex;                         // local cursor
    if (t < NB && myc > 0) gbase[t] = atomicAdd(&gcursor[t], myc);
    __syncthreads();

    for (int i = t; i < cnt; i += 512) {
        int r = row[base + i], c = col[base + i];
        int lpos = atomicAdd(&lcnt[c >> 8], 1);
        stage[lpos] = make_int2(r, c);
    }
    __syncthreads();

    for (int i = t; i < cnt; i += 512) {
        int2 p = stage[i];
        int b = p.y >> 8;
        pairs[gbase[b] + (i - lex[b])] = p.x | ((p.y & 255) << 24);
    }
}

// ---------- per-bucket final sort by dest; x8-padded esrc segments; deg ----------
__global__ __launch_bounds__(512) void k_bucket(const int* __restrict__ pairs,
                                                const int* __restrict__ rawBase,
                                                const int* __restrict__ padBase,
                                                int* __restrict__ rowptr,
                                                int* __restrict__ deg,
                                                int* __restrict__ esrc,
                                                int N, int NB) {
    __shared__ int dcnt[256];
    __shared__ int sr[256], sp[256];
    __shared__ int cur[256];
    __shared__ int outbuf[BCAP];         // 28 KB
    int t = threadIdx.x, b = blockIdx.x;
    int d0 = b << 8;
    int nd = min(256, N - d0);
    int bstart = rawBase[b];
    int cnt = rawBase[b + 1] - bstart;
    int pstart = padBase[b];

    if (t < 256) dcnt[t] = 0;
    __syncthreads();
    for (int i = t; i < cnt; i += 512) {
        unsigned p = (unsigned)pairs[bstart + i];
        atomicAdd(&dcnt[p >> 24], 1);
    }
    __syncthreads();

    int myc = 0, myp = 0;
    if (t < 256) {
        myc = dcnt[t];
        myp = (myc + 7) & ~7;
        sr[t] = myc; sp[t] = myp;
    }
    __syncthreads();
    for (int off = 1; off < 256; off <<= 1) {
        int a = 0, c2 = 0;
        if (t < 256 && t >= off) { a = sr[t - off]; c2 = sp[t - off]; }
        __syncthreads();
        if (t < 256) { sr[t] += a; sp[t] += c2; }
        __syncthreads();
    }
    if (t < 256) {
        int pex = sp[t] - myp;
        cur[t] = pex;
        if (t < nd) {
            rowptr[d0 + t] = pstart + pex;
            deg[d0 + t] = myc;            // degree for free
        }
    }
    __syncthreads();
    int pcnt = sp[255];

    if (pcnt <= BCAP) {
        for (int i = t; i < cnt; i += 512) {
            unsigned p = (unsigned)pairs[bstart + i];
            int lpos = atomicAdd(&cur[p >> 24], 1);
            outbuf[lpos] = (int)(p & 0xFFFFFF);
        }
        __syncthreads();
        if (t < 256) {
            int pex = sp[t] - myp;
            for (int j = myc; j < myp; ++j) outbuf[pex + j] = N;   // sentinel pad
        }
        __syncthreads();
        for (int i = t; i < pcnt; i += 512) esrc[pstart + i] = outbuf[i];
    } else {
        for (int i = t; i < cnt; i += 512) {
            unsigned p = (unsigned)pairs[bstart + i];
            int lpos = atomicAdd(&cur[p >> 24], 1);
            esrc[pstart + lpos] = (int)(p & 0xFFFFFF);
        }
        __syncthreads();
        if (t < 256) {
            int pex = sp[t] - myp;
            for (int j = myc; j < myp; ++j) esrc[pstart + pex + j] = N;
        }
    }
}

// ---------- GEMM1 via MFMA: h1' = (x@W1)*dinv, hi/lo fp16 split ----------
__global__ __launch_bounds__(256) void k_gemm1m(const float* __restrict__ x,
                                                const _Float16* __restrict__ W1th,
                                                const _Float16* __restrict__ W1tl,
                                                const int* __restrict__ deg,
                                                __half* __restrict__ h1, int N) {
    __shared__ alignas(16) _Float16 Wh[H1 * WTS];   // 16.5 KB
    __shared__ alignas(16) _Float16 Wl[H1 * WTS];   // 16.5 KB
    int t = threadIdx.x;

    {   // stage both planes: 8448 halves = 1056 uint4 each
        const uint4* sh = (const uint4*)W1th;
        const uint4* sl = (const uint4*)W1tl;
        uint4* dh = (uint4*)Wh;
        uint4* dl = (uint4*)Wl;
        for (int i = t; i < (H1 * WTS) / 8; i += 256) { dh[i] = sh[i]; dl[i] = sl[i]; }
    }

    int wv = t >> 6, l = t & 63;
    int col = l & 15;             // node within 16-tile (and A-row lane index)
    int krow = l >> 4;            // 0..3
    int node = blockIdx.x * 64 + wv * 16 + col;
    int nodec = min(node, N - 1);

    // B fragments from x: lane holds x[node][kt*16 + krow*4 + 0..3]
    half4_t bh[8], bl[8];
    const float4* xr = (const float4*)(x + (size_t)nodec * FIN);
#pragma unroll
    for (int kt = 0; kt < 8; ++kt) {
        float4 v = xr[kt * 4 + krow];
        half4_t hi, lo;
        hi[0] = (_Float16)v.x; lo[0] = (_Float16)(v.x - (float)hi[0]);
        hi[1] = (_Float16)v.y; lo[1] = (_Float16)(v.y - (float)hi[1]);
        hi[2] = (_Float16)v.z; lo[2] = (_Float16)(v.z - (float)hi[2]);
        hi[3] = (_Float16)v.w; lo[3] = (_Float16)(v.w - (float)hi[3]);
        bh[kt] = hi; bl[kt] = lo;
    }
    float dcv = rsqrtf((float)deg[nodec] + 1.0f);
    __syncthreads();

    float4_t acc[4];
#pragma unroll
    for (int ot = 0; ot < 4; ++ot) acc[ot] = (float4_t){0.f, 0.f, 0.f, 0.f};

#pragma unroll
    for (int kt = 0; kt < 8; ++kt) {
#pragma unroll
        for (int ot = 0; ot < 4; ++ot) {
            int aoff = ((ot * 16 + col) * WTS + kt * 16 + krow * 4) >> 2;  // half4 units
            half4_t ah = ((const half4_t*)Wh)[aoff];
            half4_t al = ((const half4_t*)Wl)[aoff];
            acc[ot] = __builtin_amdgcn_mfma_f32_16x16x16f16(ah, bh[kt], acc[ot], 0, 0, 0);
            acc[ot] = __builtin_amdgcn_mfma_f32_16x16x16f16(ah, bl[kt], acc[ot], 0, 0, 0);
            acc[ot] = __builtin_amdgcn_mfma_f32_16x16x16f16(al, bh[kt], acc[ot], 0, 0, 0);
        }
    }

    if (node < N) {
#pragma unroll
        for (int ot = 0; ot < 4; ++ot) {
            union { __half h[4]; uint2 u; } pk;
#pragma unroll
            for (int r = 0; r < 4; ++r) pk.h[r] = __float2half_rn(acc[ot][r] * dcv);
            *(uint2*)&h1[(size_t)node * H1 + ot * 16 + krow * 4] = pk.u;
        }
    }
}

// ---------- fused agg1 + bias + ReLU + GEMM2(MFMA) per 64-node block ----------
// 512 threads = 8 waves. Aggregation: R17 shape + esrc prefetch pipeline
// (next iteration's int4 index loads issue while current gathers in flight;
// over-read safe via esrc +8K-int tail guard). Epilogue: hs hi/lo planes
// (W2TS=68 bank floor). GEMM2: 12 16x16 MFMA tiles / 8 waves, 3 mfma/k-step.
__global__ __launch_bounds__(512) void k_agg1mm(const int* __restrict__ rowptr,
                                                const int* __restrict__ deg,
                                                const int* __restrict__ esrc,
                                                const __half* __restrict__ h1,
                                                const float* __restrict__ b1,
                                                const _Float16* __restrict__ W2th,
                                                const _Float16* __restrict__ W2tl,
                                                __half* __restrict__ g, int N) {
    __shared__ alignas(16) _Float16 hsh[64][W2TS];   // 8.7 KB
    __shared__ alignas(16) _Float16 hsl[64][W2TS];   // 8.7 KB
    __shared__ alignas(16) _Float16 Wth[48][W2TS];   // 6.5 KB
    __shared__ alignas(16) _Float16 Wtl[48][W2TS];   // 6.5 KB
    __shared__ float sdc[64];
    int t = threadIdx.x;
    int node0 = blockIdx.x * 64;

    {   // stage W2t planes: 408 uint4 each
        const uint4* sh = (const uint4*)W2th;
        const uint4* sl = (const uint4*)W2tl;
        uint4* dh = (uint4*)Wth;
        uint4* dl = (uint4*)Wtl;
        for (int i = t; i < (48 * W2TS) / 8; i += 512) { dh[i] = sh[i]; dl[i] = sl[i]; }
    }

    int wv = t >> 6, lane = t & 63;
    int half = lane >> 5;                // edge-octet selector
    int f = lane & 31;                   // feature-pair index
    float2 b1v = *(const float2*)&b1[2 * f];
    const __half2* hp = (const __half2*)h1;

    // aggregation: 8 nodes per wave, sequential (R17 loop + index prefetch)
#pragma unroll 1
    for (int j = 0; j < 8; ++j) {
        int r = wv * 8 + j;
        int node = node0 + r;
        if (node >= N) {
            if (lane < 32) { *(unsigned*)&hsh[r][2 * f] = 0u; *(unsigned*)&hsl[r][2 * f] = 0u; }
            if (lane == 0) sdc[r] = 0.f;
            continue;
        }
        int start = rowptr[node], d = deg[node];
        int d8 = (d + 7) & ~7;
        float dc = rsqrtf((float)d + 1.0f);
        float ax = 0.f, ay = 0.f;
        int i = 0;
        // prime: first iteration's indices (over-read past segment is safe)
        int4 sA = *(const int4*)&esrc[start + half * 8];
        int4 sB = *(const int4*)&esrc[start + half * 8 + 4];
#pragma unroll 1
        for (; i + 16 <= d8; i += 16) {
            int4 cA = sA, cB = sB;
            int nb = start + i + 16 + half * 8;
            sA = *(const int4*)&esrc[nb];        // next-iter indices in flight
            sB = *(const int4*)&esrc[nb + 4];    // under current gathers
            float2 v0 = __half22float2(hp[cA.x * 32 + f]);
            float2 v1 = __half22float2(hp[cA.y * 32 + f]);
            float2 v2 = __half22float2(hp[cA.z * 32 + f]);
            float2 v3 = __half22float2(hp[cA.w * 32 + f]);
            float2 v4 = __half22float2(hp[cB.x * 32 + f]);
            float2 v5 = __half22float2(hp[cB.y * 32 + f]);
            float2 v6 = __half22float2(hp[cB.z * 32 + f]);
            float2 v7 = __half22float2(hp[cB.w * 32 + f]);
            ax += ((v0.x + v1.x) + (v2.x + v3.x)) + ((v4.x + v5.x) + (v6.x + v7.x));
            ay += ((v0.y + v1.y) + (v2.y + v3.y)) + ((v4.y + v5.y) + (v6.y + v7.y));
        }
        if (i < d8) {                    // one 8-edge chunk: 4 per half
            int4 s = *(const int4*)&esrc[start + i + half * 4];
            float2 v0 = __half22float2(hp[s.x * 32 + f]);
            float2 v1 = __half22float2(hp[s.y * 32 + f]);
            float2 v2 = __half22float2(hp[s.z * 32 + f]);
            float2 v3 = __half22float2(hp[s.w * 32 + f]);
            ax += (v0.x + v1.x) + (v2.x + v3.x);
            ay += (v0.y + v1.y) + (v2.y + v3.y);
        }
        // cross-half reduce (both halves end with full sum)
        ax += __shfl(ax, lane ^ 32);
        ay += __shfl(ay, lane ^ 32);
        // self-loop (h1' already has one dinv factor) + bias + ReLU
        float2 sv = __half22float2(hp[node * 32 + f]);
        ax = fmaxf(fmaf(dc, ax + sv.x, b1v.x), 0.f);
        ay = fmaxf(fmaf(dc, ay + sv.y, b1v.y), 0.f);
        if (lane < 32) {
            // hi/lo fp16 split (exact): hs = hi + lo to ~2^-22
            _Float16 axh = (_Float16)ax;
            _Float16 ayh = (_Float16)ay;
            _Float16 axl = (_Float16)(ax - (float)axh);
            _Float16 ayl = (_Float16)(ay - (float)ayh);
            union { _Float16 h[2]; unsigned u; } ph, pl;
            ph.h[0] = axh; ph.h[1] = ayh;
            pl.h[0] = axl; pl.h[1] = ayl;
            *(unsigned*)&hsh[r][2 * f] = ph.u;
            *(unsigned*)&hsl[r][2 * f] = pl.u;
        }
        if (lane == 0) sdc[r] = dc;
    }
    __syncthreads();

    // GEMM2 via MFMA: D[64 nodes][48 cols] = hs(h/l) x W2t(h/l); 12 tiles / 8 waves.
    int l15 = lane & 15, kg = (lane >> 4) * 4;
#pragma unroll 1
    for (int tile = wv; tile < 12; tile += 8) {
        int mt = tile & 3, nt = tile >> 2;
        int arow = mt * 16 + l15;
        int bcol = nt * 16 + l15;
        float4_t acc = (float4_t){0.f, 0.f, 0.f, 0.f};
#pragma unroll
        for (int kt = 0; kt < 4; ++kt) {
            int ko = kt * 16 + kg;
            half4_t ah = *(const half4_t*)&hsh[arow][ko];
            half4_t al = *(const half4_t*)&hsl[arow][ko];
            half4_t bh = *(const half4_t*)&Wth[bcol][ko];
            half4_t bl = *(const half4_t*)&Wtl[bcol][ko];
            acc = __builtin_amdgcn_mfma_f32_16x16x16f16(ah, bh, acc, 0, 0, 0);
            acc = __builtin_amdgcn_mfma_f32_16x16x16f16(ah, bl, acc, 0, 0, 0);
            acc = __builtin_amdgcn_mfma_f32_16x16x16f16(al, bh, acc, 0, 0, 0);
        }
        int colo = nt * 16 + l15;
        if (colo < C2) {                 // cols 40-47 are zero; only <40 stored
#pragma unroll
            for (int r2 = 0; r2 < 4; ++r2) {
                int nd = mt * 16 + (lane >> 4) * 4 + r2;
                int node = node0 + nd;
                if (node < N) {
                    g[(size_t)node * GP + colo] = __float2half_rn(acc[r2] * sdc[nd]);
                }
            }
        }
    }
}

// ---------- agg2: wave per node, packed g rows, act-guarded + prefetch ----------
__global__ __launch_bounds__(256) void k_agg2(const int* __restrict__ rowptr,
                                              const int* __restrict__ deg,
                                              const int* __restrict__ esrc,
                                              const __half* __restrict__ g,
                                              const float* __restrict__ b2,
                                              float* __restrict__ out, int N) {
    int w = (int)((blockIdx.x * blockDim.x + threadIdx.x) >> 6);
    int lane = threadIdx.x & 63;
    if (w >= N) return;
    int half = lane >> 5;
    int f = lane & 31;                   // feature-pair; active f<20
    bool act = f < 20;
    const __half2* gp = (const __half2*)g;  // row stride 20 half2 (80 B)

    int start = rowptr[w], d = deg[w];
    int d8 = (d + 7) & ~7;
    float dc = rsqrtf((float)d + 1.0f);
    float ax = 0.f, ay = 0.f;
    if (act) {                           // f>=20 lanes: no gathers (saved 37.5%)
        int i = 0;
        int4 sA = *(const int4*)&esrc[start + half * 8];
        int4 sB = *(const int4*)&esrc[start + half * 8 + 4];
#pragma unroll 1
        for (; i + 16 <= d8; i += 16) {
            int4 cA = sA, cB = sB;
            int nb = start + i + 16 + half * 8;
            sA = *(const int4*)&esrc[nb];
            sB = *(const int4*)&esrc[nb + 4];
            float2 v0 = __half22float2(gp[cA.x * 20 + f]);
            float2 v1 = __half22float2(gp[cA.y * 20 + f]);
            float2 v2 = __half22float2(gp[cA.z * 20 + f]);
            float2 v3 = __half22float2(gp[cA.w * 20 + f]);
            float2 v4 = __half22float2(gp[cB.x * 20 + f]);
            float2 v5 = __half22float2(gp[cB.y * 20 + f]);
            float2 v6 = __half22float2(gp[cB.z * 20 + f]);
            float2 v7 = __half22float2(gp[cB.w * 20 + f]);
            ax += ((v0.x + v1.x) + (v2.x + v3.x)) + ((v4.x + v5.x) + (v6.x + v7.x));
            ay += ((v0.y + v1.y) + (v2.y + v3.y)) + ((v4.y + v5.y) + (v6.y + v7.y));
        }
        if (i < d8) {
            int4 s = *(const int4*)&esrc[start + i + half * 4];
            float2 v0 = __half22float2(gp[s.x * 20 + f]);
            float2 v1 = __half22float2(gp[s.y * 20 + f]);
            float2 v2 = __half22float2(gp[s.z * 20 + f]);
            float2 v3 = __half22float2(gp[s.w * 20 + f]);
            ax += (v0.x + v1.x) + (v2.x + v3.x);
            ay += (v0.y + v1.y) + (v2.y + v3.y);
        }
    }
    ax += __shfl(ax, lane ^ 32);
    ay += __shfl(ay, lane ^ 32);
    if (lane < 32 && act) {
        float2 b2v = *(const float2*)&b2[2 * f];
        float2 sv = __half22float2(gp[w * 20 + f]);
        float2 o;
        o.x = fmaf(dc, ax + sv.x, b2v.x);
        o.y = fmaf(dc, ay + sv.y, b2v.y);
        *(float2*)&out[(size_t)w * C2 + 2 * f] = o;
    }
}

extern "C" void kernel_launch(void* const* d_in, const int* in_sizes, int n_in,
                              void* d_out, int out_size, void* d_ws, size_t ws_size,
                              hipStream_t stream) {
    const float* x   = (const float*)d_in[0];
    const int*   ei  = (const int*)d_in[1];
    const float* W1  = (const float*)d_in[2];
    const float* b1  = (const float*)d_in[3];
    const float* W2  = (const float*)d_in[4];
    const float* b2  = (const float*)d_in[5];
    float* out = (float*)d_out;

    const int N = in_sizes[0] / FIN;       // 100000
    const int E = in_sizes[1] / 2;         // 1600000
    const int* row = ei;
    const int* col = ei + E;

    const int NB = (N + 255) >> 8;         // 391 buckets
    const int T  = (E + TILE - 1) / TILE;  // 196 tiles
    const int EP = E + NB * 2048 + 8192;   // padded esrc + prefetch tail guard

    // workspace layout
    char* ws = (char*)d_ws;
    size_t off = 0;
    int*    bucketCnt = (int*)(ws + off);    off += (size_t)NB * 4;
    int*    rawBase   = (int*)(ws + off);    off += (size_t)(NB + 1) * 4;
    int*    padBase   = (int*)(ws + off);    off += (size_t)(NB + 1) * 4;
    int*    gcursor   = (int*)(ws + off);    off += (size_t)NB * 4;
    int*    deg       = (int*)(ws + off);    off += (size_t)N * 4;
    int*    rowptr    = (int*)(ws + off);    off += (size_t)N * 4;
    int*    pairs     = (int*)(ws + off);    off += (size_t)E * 4;
    off = (off + 15) & ~(size_t)15;
    int*    esrc      = (int*)(ws + off);    off += (size_t)EP * 4;
    off = (off + 15) & ~(size_t)15;
    _Float16* W1th    = (_Float16*)(ws + off); off += (size_t)H1 * WTS * 2;
    off = (off + 15) & ~(size_t)15;
    _Float16* W1tl    = (_Float16*)(ws + off); off += (size_t)H1 * WTS * 2;
    off = (off + 15) & ~(size_t)15;
    _Float16* W2th    = (_Float16*)(ws + off); off += (size_t)48 * W2TS * 2;
    off = (off + 15) & ~(size_t)15;
    _Float16* W2tl    = (_Float16*)(ws + off); off += (size_t)48 * W2TS * 2;
    off = (off + 15) & ~(size_t)15;
    __half* h1        = (__half*)(ws + off); off += (size_t)(N + 1) * H1 * 2;
    off = (off + 15) & ~(size_t)15;
    __half* g         = (__half*)(ws + off); off += (size_t)(N + 1) * GP * 2;

    hipMemsetAsync(bucketCnt, 0, (size_t)NB * 4, stream);

    int gblocks = (N + 63) / 64;           // 1563

    // weight prep (parallel, coalesced) — independent, launched first
    k_wprep<<<(FIN * H1 + 48 * 64 + 255) / 256, 256, 0, stream>>>(W1, W1th, W1tl, W2, W2th, W2tl);

    // CSR build: bucket histogram -> scan -> chunk-claim scatter -> bucket
    // sort (emits deg for free)
    k_hist<<<T, 256, 0, stream>>>(col, E, bucketCnt, NB);
    k_scan<<<1, 512, 0, stream>>>(bucketCnt, rawBase, padBase, gcursor, h1, g, NB, N);
    k_scatter<<<T, 512, 0, stream>>>(row, col, gcursor, pairs, E, NB);
    k_bucket<<<NB, 512, 0, stream>>>(pairs, rawBase, padBase, rowptr, deg, esrc, N, NB);

    // GEMM1 via MFMA, writes h1' = (x@W1)*dinv (needs deg => after k_bucket)
    k_gemm1m<<<gblocks, 256, 0, stream>>>(x, W1th, W1tl, deg, h1, N);

    // layer 1 aggregation + bias + ReLU + GEMM2 via MFMA (fused), writes g' = h2*dinv
    k_agg1mm<<<gblocks, 512, 0, stream>>>(rowptr, deg, esrc, h1, b1, W2th, W2tl, g, N);

    // layer 2 aggregation + bias
    k_agg2<<<((size_t)N * 64 + 255) / 256, 256, 0, stream>>>(rowptr, deg, esrc, g, b2, out, N);
}